// Round 1
// baseline (769.485 us; speedup 1.0000x reference)
//
#include <hip/hip_runtime.h>

#define HIDN 20
#define CHUNK 256
#define WARM 128

__device__ __forceinline__ float fast_sigmoid(float x) {
    // sigmoid(x) = 1 / (1 + 2^(-x*log2e))
    float e = __builtin_amdgcn_exp2f(-1.4426950408889634f * x);
    return __builtin_amdgcn_rcpf(1.0f + e);
}
__device__ __forceinline__ float fast_tanh(float x) {
    // tanh(x) = 1 - 2/(2^(2x*log2e) + 1); saturates correctly for |x| large
    float e = __builtin_amdgcn_exp2f(2.8853900817779268f * x);
    return 1.0f - 2.0f * __builtin_amdgcn_rcpf(e + 1.0f);
}

// One 64-lane wave handles TWO chunks: lanes 0..19 -> chunk 2b, lanes 32..51 -> chunk 2b+1.
// Each lane owns one hidden unit (its 4 gate rows of both layers register-resident).
// h broadcast across the 20 unit-lanes of each half via __shfl (ds_bpermute).
__global__ __launch_bounds__(64, 1)
void lstm_opt_kernel(const float* __restrict__ grad, const float* __restrict__ par,
                     const float* __restrict__ Wih0, const float* __restrict__ Whh0,
                     const float* __restrict__ bih0, const float* __restrict__ bhh0,
                     const float* __restrict__ Wih1, const float* __restrict__ Whh1,
                     const float* __restrict__ bih1, const float* __restrict__ bhh1,
                     const float* __restrict__ Wout, const float* __restrict__ bout,
                     float* __restrict__ out, int n)
{
    const int lane = threadIdx.x;          // 0..63
    const int half = lane >> 5;            // 0 or 1
    const int u    = lane & 31;            // unit index within half (valid if < 20)
    const int uc   = (u < HIDN) ? u : (HIDN - 1);
    const bool unit_lane = (u < HIDN);
    const int srcbase = lane & 32;

    const int chunk = blockIdx.x * 2 + half;
    const int t0    = chunk * CHUNK;

    // ---- load weights into registers (fully unrolled -> static indexing -> VGPRs) ----
    float wih0[4][2], whh0[4][HIDN], wih1[4][HIDN], whh1[4][HIDN], b0[4], b1[4];
#pragma unroll
    for (int g = 0; g < 4; ++g) {
        const int row = g * HIDN + uc;
        wih0[g][0] = Wih0[row * 2 + 0];
        wih0[g][1] = Wih0[row * 2 + 1];
        b0[g] = bih0[row] + bhh0[row];
        b1[g] = bih1[row] + bhh1[row];
#pragma unroll
        for (int k = 0; k < HIDN; ++k) {
            whh0[g][k] = Whh0[row * HIDN + k];
            wih1[g][k] = Wih1[row * HIDN + k];
            whh1[g][k] = Whh1[row * HIDN + k];
        }
    }
    const float w_out = Wout[uc];
    const float b_out = bout[0];

    float h0 = 0.f, c0 = 0.f, h1 = 0.f, c1 = 0.f;

    const int S = WARM + CHUNK;
    int t = t0 - WARM;

    // prefetch first x
    int tc = t < 0 ? 0 : t;
    float xg = grad[tc], xp = par[tc];

    for (int step = 0; step < S; ++step, ++t) {
        // prefetch next step's inputs (hide global latency under the matvecs)
        int tn = t + 1;
        int tcn = tn < 0 ? 0 : tn;
        if (tcn >= n) tcn = n - 1;
        const float xg_n = grad[tcn], xp_n = par[tcn];

        const bool valid = (t >= 0);

        // ---------------- layer 0 ----------------
        float a0 = b0[0] + wih0[0][0] * xg + wih0[0][1] * xp;
        float a1 = b0[1] + wih0[1][0] * xg + wih0[1][1] * xp;
        float a2 = b0[2] + wih0[2][0] * xg + wih0[2][1] * xp;
        float a3 = b0[3] + wih0[3][0] * xg + wih0[3][1] * xp;
#pragma unroll
        for (int k = 0; k < HIDN; ++k) {
            const float hk = __shfl(h0, srcbase + k);
            a0 += whh0[0][k] * hk;
            a1 += whh0[1][k] * hk;
            a2 += whh0[2][k] * hk;
            a3 += whh0[3][k] * hk;
        }
        {
            const float ig = fast_sigmoid(a0);
            const float fg = fast_sigmoid(a1);
            const float gg = fast_tanh(a2);
            const float og = fast_sigmoid(a3);
            const float cn = fg * c0 + ig * gg;
            c0 = valid ? cn : 0.f;
            h0 = valid ? og * fast_tanh(c0) : 0.f;
        }

        // ---------------- layer 1 ----------------
        a0 = b1[0]; a1 = b1[1]; a2 = b1[2]; a3 = b1[3];
#pragma unroll
        for (int k = 0; k < HIDN; ++k) {
            const float h0k = __shfl(h0, srcbase + k);
            const float h1k = __shfl(h1, srcbase + k);
            a0 += wih1[0][k] * h0k + whh1[0][k] * h1k;
            a1 += wih1[1][k] * h0k + whh1[1][k] * h1k;
            a2 += wih1[2][k] * h0k + whh1[2][k] * h1k;
            a3 += wih1[3][k] * h0k + whh1[3][k] * h1k;
        }
        {
            const float ig = fast_sigmoid(a0);
            const float fg = fast_sigmoid(a1);
            const float gg = fast_tanh(a2);
            const float og = fast_sigmoid(a3);
            const float cn = fg * c1 + ig * gg;
            c1 = valid ? cn : 0.f;
            h1 = valid ? og * fast_tanh(c1) : 0.f;
        }

        // ---------------- output head (only for the C real steps) ----------------
        if (step >= WARM) {   // uniform branch across the wave
            float partial = unit_lane ? h1 * w_out : 0.f;
#pragma unroll
            for (int m = 16; m >= 1; m >>= 1)
                partial += __shfl_xor(partial, m);   // stays within each 32-lane half
            if (u == 0 && t < n)
                out[t] = partial + b_out;
        }

        xg = xg_n; xp = xp_n;
    }
}

extern "C" void kernel_launch(void* const* d_in, const int* in_sizes, int n_in,
                              void* d_out, int out_size, void* d_ws, size_t ws_size,
                              hipStream_t stream) {
    const float* grad = (const float*)d_in[0];
    const float* par  = (const float*)d_in[1];
    const float* Wih0 = (const float*)d_in[2];
    const float* Whh0 = (const float*)d_in[3];
    const float* bih0 = (const float*)d_in[4];
    const float* bhh0 = (const float*)d_in[5];
    const float* Wih1 = (const float*)d_in[6];
    const float* Whh1 = (const float*)d_in[7];
    const float* bih1 = (const float*)d_in[8];
    const float* bhh1 = (const float*)d_in[9];
    const float* Wout = (const float*)d_in[10];
    const float* bout = (const float*)d_in[11];
    float* out = (float*)d_out;

    const int n = in_sizes[0];
    const int chunks = (n + CHUNK - 1) / CHUNK;   // 2048 for n=524288
    const int blocks = (chunks + 1) / 2;          // 2 chunks per 64-thread block

    lstm_opt_kernel<<<blocks, 64, 0, stream>>>(grad, par, Wih0, Whh0, bih0, bhh0,
                                               Wih1, Whh1, bih1, bhh1, Wout, bout,
                                               out, n);
}

// Round 2
// 487.117 us; speedup vs baseline: 1.5797x; 1.5797x over previous
//
#include <hip/hip_runtime.h>

#define HIDN 20
#define CHUNK 512
#define WARM 128
#define NB ((CHUNK + WARM) / 64)   // 10 batches of 64 steps
#define WARMB (WARM / 64)          // first 2 batches are warmup

typedef float v2f __attribute__((ext_vector_type(2)));

__device__ __forceinline__ float bcast(float v, int l) {
    return __int_as_float(__builtin_amdgcn_readlane(__float_as_int(v), l));
}
__device__ __forceinline__ v2f fma2(v2f a, v2f b, v2f c) {
    return __builtin_elementwise_fma(a, b, c);
}
__device__ __forceinline__ v2f splat2(float s) { v2f r; r.x = s; r.y = s; return r; }
__device__ __forceinline__ float sigm(float x) {
    float e = __builtin_amdgcn_exp2f(-1.4426950408889634f * x);
    return __builtin_amdgcn_rcpf(1.0f + e);
}
__device__ __forceinline__ float tanh_(float x) {
    float e = __builtin_amdgcn_exp2f(2.8853900817779268f * x);
    return 1.0f - 2.0f * __builtin_amdgcn_rcpf(e + 1.0f);
}

// One 64-lane wave = one chunk of CHUNK timesteps (WARM warmup steps discarded).
// Lane u (0..19) owns hidden unit u of both layers; weights register-resident,
// gate-pair packed (i,f) / (g,o) for v_pk_fma_f32. Hidden state broadcast via
// v_readlane -> SGPR operand of the FMAs (no shuffles, no LDS).
__global__ __launch_bounds__(64, 1)
void lstm_opt_kernel(const float* __restrict__ grad, const float* __restrict__ par,
                     const float* __restrict__ Wih0, const float* __restrict__ Whh0,
                     const float* __restrict__ bih0, const float* __restrict__ bhh0,
                     const float* __restrict__ Wih1, const float* __restrict__ Whh1,
                     const float* __restrict__ bih1, const float* __restrict__ bhh1,
                     const float* __restrict__ Wout, const float* __restrict__ bout,
                     float* __restrict__ out, int n)
{
    const int lane = threadIdx.x;                  // 0..63
    const int u    = (lane < HIDN) ? lane : (HIDN - 1);

    // ---- register weights, gate-pair packed ----
    v2f wx_if[2], wx_go[2];                        // layer0 input weights (IN=2)
    v2f b_if0, b_go0, b_if1, b_go1;                // combined biases
    v2f whh0_if[HIDN], whh0_go[HIDN];              // layer0 recurrent
    v2f wih1_if[HIDN], wih1_go[HIDN];              // layer1 input (=h0)
    v2f whh1_if[HIDN], whh1_go[HIDN];              // layer1 recurrent
    {
        const int ri = 0 * HIDN + u, rf = 1 * HIDN + u;
        const int rg = 2 * HIDN + u, ro = 3 * HIDN + u;
#pragma unroll
        for (int j = 0; j < 2; ++j) {
            wx_if[j].x = Wih0[ri * 2 + j]; wx_if[j].y = Wih0[rf * 2 + j];
            wx_go[j].x = Wih0[rg * 2 + j]; wx_go[j].y = Wih0[ro * 2 + j];
        }
        b_if0.x = bih0[ri] + bhh0[ri];  b_if0.y = bih0[rf] + bhh0[rf];
        b_go0.x = bih0[rg] + bhh0[rg];  b_go0.y = bih0[ro] + bhh0[ro];
        b_if1.x = bih1[ri] + bhh1[ri];  b_if1.y = bih1[rf] + bhh1[rf];
        b_go1.x = bih1[rg] + bhh1[rg];  b_go1.y = bih1[ro] + bhh1[ro];
#pragma unroll
        for (int k = 0; k < HIDN; ++k) {
            whh0_if[k].x = Whh0[ri * HIDN + k]; whh0_if[k].y = Whh0[rf * HIDN + k];
            whh0_go[k].x = Whh0[rg * HIDN + k]; whh0_go[k].y = Whh0[ro * HIDN + k];
            wih1_if[k].x = Wih1[ri * HIDN + k]; wih1_if[k].y = Wih1[rf * HIDN + k];
            wih1_go[k].x = Wih1[rg * HIDN + k]; wih1_go[k].y = Wih1[ro * HIDN + k];
            whh1_if[k].x = Whh1[ri * HIDN + k]; whh1_if[k].y = Whh1[rf * HIDN + k];
            whh1_go[k].x = Whh1[rg * HIDN + k]; whh1_go[k].y = Whh1[ro * HIDN + k];
        }
    }
    const float wout = Wout[u];
    const float bo   = bout[0];

    float h0 = 0.f, c0 = 0.f, h1 = 0.f, c1 = 0.f;

    const int t0     = blockIdx.x * CHUNK;
    const int tstart = t0 - WARM;

    // prefetch batch 0 inputs
    float xgv, xpv;
    {
        int ti = tstart + lane;
        ti = ti < 0 ? 0 : (ti >= n ? n - 1 : ti);
        xgv = grad[ti]; xpv = par[ti];
    }

#pragma unroll 1
    for (int b = 0; b < NB; ++b) {
        // prefetch next batch (coalesced, 64 steps of inputs per wave)
        float xgn = 0.f, xpn = 0.f;
        if (b + 1 < NB) {
            int ti = tstart + (b + 1) * 64 + lane;
            ti = ti < 0 ? 0 : (ti >= n ? n - 1 : ti);
            xgn = grad[ti]; xpn = par[ti];
        }
        const bool main_phase = (b >= WARMB);
        if (b == WARMB && blockIdx.x == 0) {
            // chunk 0: reference starts from zero state exactly here
            h0 = 0.f; c0 = 0.f; h1 = 0.f; c1 = 0.f;
        }

#pragma unroll 1
        for (int j = 0; j < 64; ++j) {
            const float xg = bcast(xgv, j);
            const float xp = bcast(xpv, j);

            // ---------------- layer 0 ----------------
            v2f aif = fma2(wx_if[0], splat2(xg), b_if0);
            v2f ago = fma2(wx_go[0], splat2(xg), b_go0);
            aif = fma2(wx_if[1], splat2(xp), aif);
            ago = fma2(wx_go[1], splat2(xp), ago);
            v2f aif_b = {0.f, 0.f}, ago_b = {0.f, 0.f};
#pragma unroll
            for (int k = 0; k < HIDN; k += 2) {
                const v2f ha = splat2(bcast(h0, k));
                const v2f hb = splat2(bcast(h0, k + 1));
                aif   = fma2(whh0_if[k],     ha, aif);
                ago   = fma2(whh0_go[k],     ha, ago);
                aif_b = fma2(whh0_if[k + 1], hb, aif_b);
                ago_b = fma2(whh0_go[k + 1], hb, ago_b);
            }
            aif += aif_b; ago += ago_b;
            {
                const float ig = sigm(aif.x);
                const float fg = sigm(aif.y);
                const float gg = tanh_(ago.x);
                const float og = sigm(ago.y);
                c0 = fg * c0 + ig * gg;
                h0 = og * tanh_(c0);
            }

            // ---------------- layer 1 ----------------
            aif = b_if1; ago = b_go1;
            aif_b.x = 0.f; aif_b.y = 0.f; ago_b.x = 0.f; ago_b.y = 0.f;
#pragma unroll
            for (int k = 0; k < HIDN; ++k) {
                const v2f h0k = splat2(bcast(h0, k));
                const v2f h1k = splat2(bcast(h1, k));
                aif   = fma2(wih1_if[k], h0k, aif);
                ago   = fma2(wih1_go[k], h0k, ago);
                aif_b = fma2(whh1_if[k], h1k, aif_b);
                ago_b = fma2(whh1_go[k], h1k, ago_b);
            }
            aif += aif_b; ago += ago_b;
            {
                const float ig = sigm(aif.x);
                const float fg = sigm(aif.y);
                const float gg = tanh_(ago.x);
                const float og = sigm(ago.y);
                c1 = fg * c1 + ig * gg;
                h1 = og * tanh_(c1);
            }

            // ---------------- output head (main phase only) ----------------
            if (main_phase) {
                float p = (lane < HIDN) ? h1 * wout : 0.f;
#pragma unroll
                for (int m = 16; m >= 1; m >>= 1)
                    p += __shfl_xor(p, m);          // sums lanes 0..31 (20..31 are zero)
                const int t = tstart + b * 64 + j;
                if (lane == 0 && t < n)
                    out[t] = p + bo;
            }
        }
        xgv = xgn; xpv = xpn;
    }
}

extern "C" void kernel_launch(void* const* d_in, const int* in_sizes, int n_in,
                              void* d_out, int out_size, void* d_ws, size_t ws_size,
                              hipStream_t stream) {
    const float* grad = (const float*)d_in[0];
    const float* par  = (const float*)d_in[1];
    const float* Wih0 = (const float*)d_in[2];
    const float* Whh0 = (const float*)d_in[3];
    const float* bih0 = (const float*)d_in[4];
    const float* bhh0 = (const float*)d_in[5];
    const float* Wih1 = (const float*)d_in[6];
    const float* Whh1 = (const float*)d_in[7];
    const float* bih1 = (const float*)d_in[8];
    const float* bhh1 = (const float*)d_in[9];
    const float* Wout = (const float*)d_in[10];
    const float* bout = (const float*)d_in[11];
    float* out = (float*)d_out;

    const int n = in_sizes[0];
    const int chunks = (n + CHUNK - 1) / CHUNK;   // 1024 for n=524288 -> 1 wave/SIMD

    lstm_opt_kernel<<<chunks, 64, 0, stream>>>(grad, par, Wih0, Whh0, bih0, bhh0,
                                               Wih1, Whh1, bih1, bhh1, Wout, bout,
                                               out, n);
}

// Round 3
// 378.218 us; speedup vs baseline: 2.0345x; 1.2879x over previous
//
#include <hip/hip_runtime.h>

#define HIDN 20
#define CHUNK 512
#define WARM 128
#define NB ((CHUNK + WARM) / 64)   // 10 batches of 64 steps
#define WARMB (WARM / 64)

__device__ __forceinline__ float bcast(float v, int l) {
    return __int_as_float(__builtin_amdgcn_readlane(__float_as_int(v), l));
}

// gate-split LSTM cell epilogue. Half A lanes hold gate pre-acts (i,f),
// half B lanes hold (g,o) for the same unit. Uniform code path:
//   gA = mA*sigm(mA*aA) - dA   (mA=1,dA=0 -> sigmoid ; mA=2,dA=1 -> tanh)
//   i*g  = gA * shfl_xor(gA,32)  (symmetric in the two halves)
//   f,o  from gB / shfl_xor(gB,32) with 2 selects
__device__ __forceinline__ float gate_update(float aA, float aB, float& c,
                                             float cA, float mA, float dA,
                                             bool hB) {
    const float cB = -1.4426950408889634f;
    const float cT =  2.8853900817779268f;
    float eA = __builtin_amdgcn_exp2f(cA * aA);
    float sA = __builtin_amdgcn_rcpf(1.0f + eA);
    float gA = __builtin_fmaf(mA, sA, -dA);          // i (half A) / g (half B)
    float eB = __builtin_amdgcn_exp2f(cB * aB);
    float gB = __builtin_amdgcn_rcpf(1.0f + eB);     // f (half A) / o (half B)
    float oA = __shfl_xor(gA, 32);
    float oB = __shfl_xor(gB, 32);
    float f = hB ? oB : gB;
    float o = hB ? gB : oB;
    c = __builtin_fmaf(f, c, gA * oA);
    float ec = __builtin_amdgcn_exp2f(cT * c);
    float tc = 1.0f - 2.0f * __builtin_amdgcn_rcpf(ec + 1.0f);
    return o * tc;
}

#define RKA(M) M(0) M(1) M(2) M(3) M(4) M(5) M(6) M(7) M(8) M(9)
#define RKB(M) M(10) M(11) M(12) M(13) M(14) M(15) M(16) M(17) M(18) M(19)
#define RK(M) RKA(M) RKB(M)

// One 64-lane wave = one chunk of CHUNK steps (WARM discarded warmup steps).
// All weights in NAMED scalar registers (no arrays -> no scratch).
__global__ __launch_bounds__(64, 1)
void lstm_opt_kernel(const float* __restrict__ grad, const float* __restrict__ par,
                     const float* __restrict__ Wih0, const float* __restrict__ Whh0,
                     const float* __restrict__ bih0, const float* __restrict__ bhh0,
                     const float* __restrict__ Wih1, const float* __restrict__ Whh1,
                     const float* __restrict__ bih1, const float* __restrict__ bhh1,
                     const float* __restrict__ Wout, const float* __restrict__ bout,
                     float* __restrict__ out, int n)
{
    const int lane  = threadIdx.x;
    const int lh    = lane & 31;
    const bool hB   = lane >= 32;
    const int u     = (lh < HIDN) ? lh : (HIDN - 1);
    const bool valid = (lh < HIDN);

    const int rowA = (hB ? 2 : 0) * HIDN + u;   // i-row or g-row
    const int rowB = (hB ? 3 : 1) * HIDN + u;   // f-row or o-row

#define DECLW(k) float w0a_##k, w0b_##k, wia_##k, wib_##k, wha_##k, whb_##k;
    RK(DECLW)
#undef DECLW
#define LOADW(k) \
    w0a_##k = Whh0[rowA * HIDN + k]; w0b_##k = Whh0[rowB * HIDN + k]; \
    wia_##k = Wih1[rowA * HIDN + k]; wib_##k = Wih1[rowB * HIDN + k]; \
    wha_##k = Whh1[rowA * HIDN + k]; whb_##k = Whh1[rowB * HIDN + k];
    RK(LOADW)
#undef LOADW

    const float wxAg = Wih0[rowA * 2 + 0], wxAp = Wih0[rowA * 2 + 1];
    const float wxBg = Wih0[rowB * 2 + 0], wxBp = Wih0[rowB * 2 + 1];
    const float bA0 = bih0[rowA] + bhh0[rowA];
    const float bB0 = bih0[rowB] + bhh0[rowB];
    const float bA1 = bih1[rowA] + bhh1[rowA];
    const float bB1 = bih1[rowB] + bhh1[rowB];
    const float wo  = valid ? Wout[u] : 0.f;
    const float bo  = bout[0];

    const float mA = hB ? 2.0f : 1.0f;
    const float dA = hB ? 1.0f : 0.0f;
    const float cA = -1.4426950408889634f * mA;

    float h0 = 0.f, c0 = 0.f, h1 = 0.f, c1 = 0.f;
#define DECLS(k) float sh0_##k = 0.f, sh1_##k = 0.f;
    RK(DECLS)
#undef DECLS

    const int t0     = blockIdx.x * CHUNK;
    const int tstart = t0 - WARM;

    float xgv, xpv;
    { int ti = tstart + lane; ti = ti < 0 ? 0 : ti; xgv = grad[ti]; xpv = par[ti]; }

    float rbuf = 0.f;

#pragma unroll 1
    for (int b = 0; b < NB; ++b) {
        float xgn = 0.f, xpn = 0.f;
        if (b + 1 < NB) {
            int ti = tstart + (b + 1) * 64 + lane;
            ti = ti < 0 ? 0 : (ti >= n ? n - 1 : ti);
            xgn = grad[ti]; xpn = par[ti];
        }
        if (b == WARMB && blockIdx.x == 0) {
            // chunk 0: reference's true zero initial state starts exactly here
            h0 = 0.f; c0 = 0.f; h1 = 0.f; c1 = 0.f;
#define ZS(k) sh0_##k = 0.f; sh1_##k = 0.f;
            RK(ZS)
#undef ZS
        }
        const bool main_phase = (b >= WARMB);

#pragma unroll 2
        for (int j = 0; j < 64; ++j) {
            const float xg = bcast(xgv, j);
            const float xp = bcast(xpv, j);

            // ---------------- layer 0 (uses h0_old broadcasts sh0_*) ----------------
            float aA  = __builtin_fmaf(wxAp, xp, __builtin_fmaf(wxAg, xg, bA0));
            float aB  = __builtin_fmaf(wxBp, xp, __builtin_fmaf(wxBg, xg, bB0));
            float aA2 = 0.f, aB2 = 0.f;
#define F0A(k)  aA  = __builtin_fmaf(w0a_##k, sh0_##k, aA);
#define F0A2(k) aA2 = __builtin_fmaf(w0a_##k, sh0_##k, aA2);
#define F0B(k)  aB  = __builtin_fmaf(w0b_##k, sh0_##k, aB);
#define F0B2(k) aB2 = __builtin_fmaf(w0b_##k, sh0_##k, aB2);
            RKA(F0A) RKB(F0A2) RKA(F0B) RKB(F0B2)
#undef F0A
#undef F0A2
#undef F0B
#undef F0B2
            aA += aA2; aB += aB2;
            h0 = gate_update(aA, aB, c0, cA, mA, dA, hB);
#define RD0(k) sh0_##k = bcast(h0, k);
            RK(RD0)
#undef RD0

            // ---------------- layer 1 (uses h0_new and h1_old) ----------------
            float qa0 = bA1, qa1 = 0.f, qa2 = 0.f, qa3 = 0.f;
            float qb0 = bB1, qb1 = 0.f, qb2 = 0.f, qb3 = 0.f;
#define F1A(k)  qa0 = __builtin_fmaf(wia_##k, sh0_##k, qa0);
#define F1A2(k) qa1 = __builtin_fmaf(wia_##k, sh0_##k, qa1);
#define F1H(k)  qa2 = __builtin_fmaf(wha_##k, sh1_##k, qa2);
#define F1H2(k) qa3 = __builtin_fmaf(wha_##k, sh1_##k, qa3);
#define G1A(k)  qb0 = __builtin_fmaf(wib_##k, sh0_##k, qb0);
#define G1A2(k) qb1 = __builtin_fmaf(wib_##k, sh0_##k, qb1);
#define G1H(k)  qb2 = __builtin_fmaf(whb_##k, sh1_##k, qb2);
#define G1H2(k) qb3 = __builtin_fmaf(whb_##k, sh1_##k, qb3);
            RKA(F1A) RKB(F1A2) RKA(F1H) RKB(F1H2)
            RKA(G1A) RKB(G1A2) RKA(G1H) RKB(G1H2)
#undef F1A
#undef F1A2
#undef F1H
#undef F1H2
#undef G1A
#undef G1A2
#undef G1H
#undef G1H2
            float a1A = (qa0 + qa1) + (qa2 + qa3);
            float a1B = (qb0 + qb1) + (qb2 + qb3);
            h1 = gate_update(a1A, a1B, c1, cA, mA, dA, hB);
#define RD1(k) sh1_##k = bcast(h1, k);
            RK(RD1)
#undef RD1

            // ---------------- output head ----------------
            if (main_phase) {
                float p = h1 * wo;                 // wo==0 on pad lanes; both halves identical
                p += __shfl_xor(p, 16);
                p += __shfl_xor(p, 8);
                p += __shfl_xor(p, 4);
                p += __shfl_xor(p, 2);
                p += __shfl_xor(p, 1);
                rbuf = (lane == j) ? (p + bo) : rbuf;
            }
        }
        if (main_phase) {
            int t = tstart + b * 64 + lane;
            if (t >= 0 && t < n) out[t] = rbuf;    // coalesced, once per 64 steps
        }
        xgv = xgn; xpv = xpn;
    }
}

extern "C" void kernel_launch(void* const* d_in, const int* in_sizes, int n_in,
                              void* d_out, int out_size, void* d_ws, size_t ws_size,
                              hipStream_t stream) {
    const float* grad = (const float*)d_in[0];
    const float* par  = (const float*)d_in[1];
    const float* Wih0 = (const float*)d_in[2];
    const float* Whh0 = (const float*)d_in[3];
    const float* bih0 = (const float*)d_in[4];
    const float* bhh0 = (const float*)d_in[5];
    const float* Wih1 = (const float*)d_in[6];
    const float* Whh1 = (const float*)d_in[7];
    const float* bih1 = (const float*)d_in[8];
    const float* bhh1 = (const float*)d_in[9];
    const float* Wout = (const float*)d_in[10];
    const float* bout = (const float*)d_in[11];
    float* out = (float*)d_out;

    const int n = in_sizes[0];
    const int chunks = (n + CHUNK - 1) / CHUNK;   // 1024 for n=524288

    lstm_opt_kernel<<<chunks, 64, 0, stream>>>(grad, par, Wih0, Whh0, bih0, bhh0,
                                               Wih1, Whh1, bih1, bhh1, Wout, bout,
                                               out, n);
}

// Round 4
// 339.082 us; speedup vs baseline: 2.2693x; 1.1154x over previous
//
#include <hip/hip_runtime.h>

#define HIDN 20
#define CHUNK 256
#define WARM 128
#define NB ((CHUNK + WARM) / 64)   // 6 batches of 64 steps
#define WARMB (WARM / 64)          // first 2 batches are warmup

__device__ __forceinline__ float bcast(float v, int l) {
    return __int_as_float(__builtin_amdgcn_readlane(__float_as_int(v), l));
}

// gate-split LSTM cell epilogue. Half A lanes hold gate pre-acts (i,f),
// half B lanes hold (g,o) for the same unit.
__device__ __forceinline__ float gate_update(float aA, float aB, float& c,
                                             float cA, float mA, float dA,
                                             bool hB) {
    const float cB = -1.4426950408889634f;
    const float cT =  2.8853900817779268f;
    float eA = __builtin_amdgcn_exp2f(cA * aA);
    float sA = __builtin_amdgcn_rcpf(1.0f + eA);
    float gA = __builtin_fmaf(mA, sA, -dA);          // i (half A) / g (half B)
    float eB = __builtin_amdgcn_exp2f(cB * aB);
    float gB = __builtin_amdgcn_rcpf(1.0f + eB);     // f (half A) / o (half B)
    float oA = __shfl_xor(gA, 32);
    float oB = __shfl_xor(gB, 32);
    float f = hB ? oB : gB;
    float o = hB ? gB : oB;
    c = __builtin_fmaf(f, c, gA * oA);
    float ec = __builtin_amdgcn_exp2f(cT * c);
    float tc = 1.0f - 2.0f * __builtin_amdgcn_rcpf(ec + 1.0f);
    return o * tc;
}

#define RKA(M) M(0) M(1) M(2) M(3) M(4) M(5) M(6) M(7) M(8) M(9)
#define RKB(M) M(10) M(11) M(12) M(13) M(14) M(15) M(16) M(17) M(18) M(19)
#define RK(M) RKA(M) RKB(M)

// One 64-lane wave = one chunk of CHUNK steps (WARM discarded warmup steps).
// All weights in NAMED scalar registers, pinned via opaque asm so the
// allocator can neither rematerialize the loads nor sink them into the loop.
// waves_per_eu(2,2): target exactly 2 waves/SIMD (VGPR budget 256).
__global__ __launch_bounds__(64)
__attribute__((amdgpu_waves_per_eu(2, 2)))
void lstm_opt_kernel(const float* __restrict__ grad, const float* __restrict__ par,
                     const float* __restrict__ Wih0, const float* __restrict__ Whh0,
                     const float* __restrict__ bih0, const float* __restrict__ bhh0,
                     const float* __restrict__ Wih1, const float* __restrict__ Whh1,
                     const float* __restrict__ bih1, const float* __restrict__ bhh1,
                     const float* __restrict__ Wout, const float* __restrict__ bout,
                     float* __restrict__ out, int n)
{
    const int lane  = threadIdx.x;
    const int lh    = lane & 31;
    const bool hB   = lane >= 32;
    const int u     = (lh < HIDN) ? lh : (HIDN - 1);
    const bool valid = (lh < HIDN);

    const int rowA = (hB ? 2 : 0) * HIDN + u;   // i-row or g-row
    const int rowB = (hB ? 3 : 1) * HIDN + u;   // f-row or o-row

#define DECLW(k) float w0a_##k, w0b_##k, wia_##k, wib_##k, wha_##k, whb_##k;
    RK(DECLW)
#undef DECLW
#define LOADW(k) \
    w0a_##k = Whh0[rowA * HIDN + k]; w0b_##k = Whh0[rowB * HIDN + k]; \
    wia_##k = Wih1[rowA * HIDN + k]; wib_##k = Wih1[rowB * HIDN + k]; \
    wha_##k = Whh1[rowA * HIDN + k]; whb_##k = Whh1[rowB * HIDN + k];
    RK(LOADW)
#undef LOADW

    float wxAg = Wih0[rowA * 2 + 0], wxAp = Wih0[rowA * 2 + 1];
    float wxBg = Wih0[rowB * 2 + 0], wxBp = Wih0[rowB * 2 + 1];
    float bA0 = bih0[rowA] + bhh0[rowA];
    float bB0 = bih0[rowB] + bhh0[rowB];
    float bA1 = bih1[rowA] + bhh1[rowA];
    float bB1 = bih1[rowB] + bhh1[rowB];
    float wo  = valid ? Wout[u] : 0.f;
    const float bo = bout[0];

    // ---- pin all per-lane constants into VGPRs (defeat remat/sinking) ----
#define PINW(k) asm volatile("" : "+v"(w0a_##k), "+v"(w0b_##k), "+v"(wia_##k), \
                                  "+v"(wib_##k), "+v"(wha_##k), "+v"(whb_##k));
    RK(PINW)
#undef PINW
    asm volatile("" : "+v"(wxAg), "+v"(wxAp), "+v"(wxBg), "+v"(wxBp));
    asm volatile("" : "+v"(bA0), "+v"(bB0), "+v"(bA1), "+v"(bB1), "+v"(wo));

    const float mA = hB ? 2.0f : 1.0f;
    const float dA = hB ? 1.0f : 0.0f;
    const float cA = -1.4426950408889634f * mA;

    float h0 = 0.f, c0 = 0.f, h1 = 0.f, c1 = 0.f;
#define DECLS(k) float sh0_##k = 0.f, sh1_##k = 0.f;
    RK(DECLS)
#undef DECLS

    const int t0     = blockIdx.x * CHUNK;
    const int tstart = t0 - WARM;

    float xgv, xpv;
    { int ti = tstart + lane; ti = ti < 0 ? 0 : ti; xgv = grad[ti]; xpv = par[ti]; }

    float rbuf = 0.f;

#pragma unroll 1
    for (int b = 0; b < NB; ++b) {
        float xgn = 0.f, xpn = 0.f;
        if (b + 1 < NB) {
            int ti = tstart + (b + 1) * 64 + lane;
            ti = ti < 0 ? 0 : (ti >= n ? n - 1 : ti);
            xgn = grad[ti]; xpn = par[ti];
        }
        if (b == WARMB && blockIdx.x == 0) {
            // chunk 0: reference's true zero initial state starts exactly here
            h0 = 0.f; c0 = 0.f; h1 = 0.f; c1 = 0.f;
#define ZS(k) sh0_##k = 0.f; sh1_##k = 0.f;
            RK(ZS)
#undef ZS
        }
        const bool main_phase = (b >= WARMB);

#pragma unroll 2
        for (int j = 0; j < 64; ++j) {
            const float xg = bcast(xgv, j);
            const float xp = bcast(xpv, j);

            // ---------------- layer 0 (uses h0_old broadcasts sh0_*) ----------------
            float aA  = __builtin_fmaf(wxAp, xp, __builtin_fmaf(wxAg, xg, bA0));
            float aB  = __builtin_fmaf(wxBp, xp, __builtin_fmaf(wxBg, xg, bB0));
            float aA2 = 0.f, aB2 = 0.f;
#define F0A(k)  aA  = __builtin_fmaf(w0a_##k, sh0_##k, aA);
#define F0A2(k) aA2 = __builtin_fmaf(w0a_##k, sh0_##k, aA2);
#define F0B(k)  aB  = __builtin_fmaf(w0b_##k, sh0_##k, aB);
#define F0B2(k) aB2 = __builtin_fmaf(w0b_##k, sh0_##k, aB2);
            RKA(F0A) RKB(F0A2) RKA(F0B) RKB(F0B2)
#undef F0A
#undef F0A2
#undef F0B
#undef F0B2
            aA += aA2; aB += aB2;
            h0 = gate_update(aA, aB, c0, cA, mA, dA, hB);
#define RD0(k) sh0_##k = bcast(h0, k);
            RK(RD0)
#undef RD0

            // ---------------- layer 1 (uses h0_new and h1_old) ----------------
            float qa0 = bA1, qa1 = 0.f, qa2 = 0.f, qa3 = 0.f;
            float qb0 = bB1, qb1 = 0.f, qb2 = 0.f, qb3 = 0.f;
#define F1A(k)  qa0 = __builtin_fmaf(wia_##k, sh0_##k, qa0);
#define F1A2(k) qa1 = __builtin_fmaf(wia_##k, sh0_##k, qa1);
#define F1H(k)  qa2 = __builtin_fmaf(wha_##k, sh1_##k, qa2);
#define F1H2(k) qa3 = __builtin_fmaf(wha_##k, sh1_##k, qa3);
#define G1A(k)  qb0 = __builtin_fmaf(wib_##k, sh0_##k, qb0);
#define G1A2(k) qb1 = __builtin_fmaf(wib_##k, sh0_##k, qb1);
#define G1H(k)  qb2 = __builtin_fmaf(whb_##k, sh1_##k, qb2);
#define G1H2(k) qb3 = __builtin_fmaf(whb_##k, sh1_##k, qb3);
            RKA(F1A) RKB(F1A2) RKA(F1H) RKB(F1H2)
            RKA(G1A) RKB(G1A2) RKA(G1H) RKB(G1H2)
#undef F1A
#undef F1A2
#undef F1H
#undef F1H2
#undef G1A
#undef G1A2
#undef G1H
#undef G1H2
            float a1A = (qa0 + qa1) + (qa2 + qa3);
            float a1B = (qb0 + qb1) + (qb2 + qb3);
            h1 = gate_update(a1A, a1B, c1, cA, mA, dA, hB);
#define RD1(k) sh1_##k = bcast(h1, k);
            RK(RD1)
#undef RD1

            // ---------------- output head ----------------
            if (main_phase) {
                float p = h1 * wo;                 // wo==0 on pad lanes; both halves identical
                p += __shfl_xor(p, 16);
                p += __shfl_xor(p, 8);
                p += __shfl_xor(p, 4);
                p += __shfl_xor(p, 2);
                p += __shfl_xor(p, 1);
                rbuf = (lane == j) ? (p + bo) : rbuf;
            }
        }
        if (main_phase) {
            int t = tstart + b * 64 + lane;
            if (t >= 0 && t < n) out[t] = rbuf;    // coalesced, once per 64 steps
        }
        xgv = xgn; xpv = xpn;
    }
}

extern "C" void kernel_launch(void* const* d_in, const int* in_sizes, int n_in,
                              void* d_out, int out_size, void* d_ws, size_t ws_size,
                              hipStream_t stream) {
    const float* grad = (const float*)d_in[0];
    const float* par  = (const float*)d_in[1];
    const float* Wih0 = (const float*)d_in[2];
    const float* Whh0 = (const float*)d_in[3];
    const float* bih0 = (const float*)d_in[4];
    const float* bhh0 = (const float*)d_in[5];
    const float* Wih1 = (const float*)d_in[6];
    const float* Whh1 = (const float*)d_in[7];
    const float* bih1 = (const float*)d_in[8];
    const float* bhh1 = (const float*)d_in[9];
    const float* Wout = (const float*)d_in[10];
    const float* bout = (const float*)d_in[11];
    float* out = (float*)d_out;

    const int n = in_sizes[0];
    const int chunks = (n + CHUNK - 1) / CHUNK;   // 2048 for n=524288 -> 2 waves/SIMD

    lstm_opt_kernel<<<chunks, 64, 0, stream>>>(grad, par, Wih0, Whh0, bih0, bhh0,
                                               Wih1, Whh1, bih1, bhh1, Wout, bout,
                                               out, n);
}

// Round 6
// 296.326 us; speedup vs baseline: 2.5968x; 1.1443x over previous
//
#include <hip/hip_runtime.h>

#define HIDN 20
#define CHUNK 256
#define WARM 128
#define NB ((CHUNK + WARM) / 64)   // 6 batches of 64 steps
#define WARMB (WARM / 64)          // first 2 batches are warmup

typedef float v2f __attribute__((ext_vector_type(2)));

__device__ __forceinline__ float bcast(float v, int l) {
    return __int_as_float(__builtin_amdgcn_readlane(__float_as_int(v), l));
}
__device__ __forceinline__ v2f fma2(v2f a, v2f b, v2f c) {
    return __builtin_elementwise_fma(a, b, c);      // -> v_pk_fma_f32
}
__device__ __forceinline__ v2f splat2(float s) { v2f r; r.x = s; r.y = s; return r; }

// gate-split LSTM cell epilogue (f32). Half A lanes hold gate pre-acts (i,f),
// half B lanes hold (g,o) for the same unit.
__device__ __forceinline__ float gate_update(float aA, float aB, float& c,
                                             float cA, float mA, float dA,
                                             bool hB) {
    const float cB = -1.4426950408889634f;
    const float cT =  2.8853900817779268f;
    float eA = __builtin_amdgcn_exp2f(cA * aA);
    float sA = __builtin_amdgcn_rcpf(1.0f + eA);
    float gA = __builtin_fmaf(mA, sA, -dA);          // i (half A) / g (half B)
    float eB = __builtin_amdgcn_exp2f(cB * aB);
    float gB = __builtin_amdgcn_rcpf(1.0f + eB);     // f (half A) / o (half B)
    float oA = __shfl_xor(gA, 32);
    float oB = __shfl_xor(gB, 32);
    float f = hB ? oB : gB;
    float o = hB ? gB : oB;
    c = __builtin_fmaf(f, c, gA * oA);
    float ec = __builtin_amdgcn_exp2f(cT * c);
    float tc = 1.0f - 2.0f * __builtin_amdgcn_rcpf(ec + 1.0f);
    return o * tc;
}

#define RKA(M) M(0) M(1) M(2) M(3) M(4) M(5) M(6) M(7) M(8) M(9)
#define RKB(M) M(10) M(11) M(12) M(13) M(14) M(15) M(16) M(17) M(18) M(19)
#define RK(M) RKA(M) RKB(M)

// One 64-lane wave = one chunk of CHUNK steps (WARM discarded warmup steps).
// Each lane's TWO gate rows (A,B) are interleaved as named float2 pairs and
// consumed by v_pk_fma_f32 against the readlane-broadcast h (SGPR operand).
// All f32 — numerics identical to the round-4 kernel that passed at 4.9e-4.
__global__ __launch_bounds__(64)
__attribute__((amdgpu_waves_per_eu(2, 2)))
void lstm_opt_kernel(const float* __restrict__ grad, const float* __restrict__ par,
                     const float* __restrict__ Wih0, const float* __restrict__ Whh0,
                     const float* __restrict__ bih0, const float* __restrict__ bhh0,
                     const float* __restrict__ Wih1, const float* __restrict__ Whh1,
                     const float* __restrict__ bih1, const float* __restrict__ bhh1,
                     const float* __restrict__ Wout, const float* __restrict__ bout,
                     float* __restrict__ out, int n)
{
    const int lane  = threadIdx.x;
    const int lh    = lane & 31;
    const bool hB   = lane >= 32;
    const int u     = (lh < HIDN) ? lh : (HIDN - 1);
    const bool valid = (lh < HIDN);

    const int rowA = (hB ? 2 : 0) * HIDN + u;   // i-row or g-row
    const int rowB = (hB ? 3 : 1) * HIDN + u;   // f-row or o-row

    // ---- paired register weights (named float2 scalars; no arrays) ----
#define DECLW(k) v2f w0_##k, wi_##k, wh_##k;
    RK(DECLW)
#undef DECLW
#define LOADW(k) \
    w0_##k.x = Whh0[rowA * HIDN + k]; w0_##k.y = Whh0[rowB * HIDN + k]; \
    wi_##k.x = Wih1[rowA * HIDN + k]; wi_##k.y = Wih1[rowB * HIDN + k]; \
    wh_##k.x = Whh1[rowA * HIDN + k]; wh_##k.y = Whh1[rowB * HIDN + k];
    RK(LOADW)
#undef LOADW

    v2f wxg, wxp, b0p, b1p;
    wxg.x = Wih0[rowA * 2 + 0]; wxg.y = Wih0[rowB * 2 + 0];
    wxp.x = Wih0[rowA * 2 + 1]; wxp.y = Wih0[rowB * 2 + 1];
    b0p.x = bih0[rowA] + bhh0[rowA]; b0p.y = bih0[rowB] + bhh0[rowB];
    b1p.x = bih1[rowA] + bhh1[rowA]; b1p.y = bih1[rowB] + bhh1[rowB];
    float wo = valid ? Wout[u] : 0.f;
    const float bo = bout[0];

    // ---- pin per-lane constants into VGPRs (defeat remat/sinking) ----
#define PINW(k) asm volatile("" : "+v"(w0_##k), "+v"(wi_##k), "+v"(wh_##k));
    RK(PINW)
#undef PINW
    asm volatile("" : "+v"(wxg), "+v"(wxp), "+v"(b0p), "+v"(b1p), "+v"(wo));

    const float mA = hB ? 2.0f : 1.0f;
    const float dA = hB ? 1.0f : 0.0f;
    const float cA = -1.4426950408889634f * mA;

    float h0 = 0.f, c0 = 0.f, h1 = 0.f, c1 = 0.f;
#define DECLS(k) float sh0_##k = 0.f, sh1_##k = 0.f;
    RK(DECLS)
#undef DECLS

    const int t0     = blockIdx.x * CHUNK;
    const int tstart = t0 - WARM;

    float xgv, xpv;
    { int ti = tstart + lane; ti = ti < 0 ? 0 : ti; xgv = grad[ti]; xpv = par[ti]; }

    float rbuf = 0.f;

#pragma unroll 1
    for (int b = 0; b < NB; ++b) {
        float xgn = 0.f, xpn = 0.f;
        if (b + 1 < NB) {
            int ti = tstart + (b + 1) * 64 + lane;
            ti = ti < 0 ? 0 : (ti >= n ? n - 1 : ti);
            xgn = grad[ti]; xpn = par[ti];
        }
        if (b == WARMB && blockIdx.x == 0) {
            // chunk 0: reference's true zero initial state starts exactly here
            h0 = 0.f; c0 = 0.f; h1 = 0.f; c1 = 0.f;
#define ZS(k) sh0_##k = 0.f; sh1_##k = 0.f;
            RK(ZS)
#undef ZS
        }
        const bool main_phase = (b >= WARMB);

#pragma unroll 2
        for (int j = 0; j < 64; ++j) {
            const float xg = bcast(xgv, j);
            const float xp = bcast(xpv, j);

            // ---------------- layer 0 (h0_old broadcasts sh0_*) ----------------
            v2f a  = fma2(wxp, splat2(xp), fma2(wxg, splat2(xg), b0p));
            v2f a2 = {0.f, 0.f};
#define F0A(k)  a  = fma2(w0_##k, splat2(sh0_##k), a);
#define F0B(k)  a2 = fma2(w0_##k, splat2(sh0_##k), a2);
            RKA(F0A) RKB(F0B)
#undef F0A
#undef F0B
            a += a2;
            h0 = gate_update(a.x, a.y, c0, cA, mA, dA, hB);
#define RD0(k) sh0_##k = bcast(h0, k);
            RK(RD0)
#undef RD0

            // ---------------- layer 1 (h0_new and h1_old) ----------------
            v2f q0 = b1p, q1 = {0.f, 0.f}, q2 = {0.f, 0.f}, q3 = {0.f, 0.f};
#define F1A(k)  q0 = fma2(wi_##k, splat2(sh0_##k), q0);
#define F1B(k)  q1 = fma2(wi_##k, splat2(sh0_##k), q1);
#define F1C(k)  q2 = fma2(wh_##k, splat2(sh1_##k), q2);
#define F1D(k)  q3 = fma2(wh_##k, splat2(sh1_##k), q3);
            RKA(F1A) RKB(F1B) RKA(F1C) RKB(F1D)
#undef F1A
#undef F1B
#undef F1C
#undef F1D
            v2f a1 = (q0 + q1) + (q2 + q3);
            h1 = gate_update(a1.x, a1.y, c1, cA, mA, dA, hB);
#define RD1(k) sh1_##k = bcast(h1, k);
            RK(RD1)
#undef RD1

            // ---------------- output head (f32 shfl tree) ----------------
            if (main_phase) {
                float p = h1 * wo;                 // wo==0 on pad lanes
                p += __shfl_xor(p, 16);
                p += __shfl_xor(p, 8);
                p += __shfl_xor(p, 4);
                p += __shfl_xor(p, 2);
                p += __shfl_xor(p, 1);
                rbuf = (lane == j) ? (p + bo) : rbuf;
            }
        }
        if (main_phase) {
            int t = tstart + b * 64 + lane;
            if (t >= 0 && t < n) out[t] = rbuf;    // coalesced, once per 64 steps
        }
        xgv = xgn; xpv = xpn;
    }
}

extern "C" void kernel_launch(void* const* d_in, const int* in_sizes, int n_in,
                              void* d_out, int out_size, void* d_ws, size_t ws_size,
                              hipStream_t stream) {
    const float* grad = (const float*)d_in[0];
    const float* par  = (const float*)d_in[1];
    const float* Wih0 = (const float*)d_in[2];
    const float* Whh0 = (const float*)d_in[3];
    const float* bih0 = (const float*)d_in[4];
    const float* bhh0 = (const float*)d_in[5];
    const float* Wih1 = (const float*)d_in[6];
    const float* Whh1 = (const float*)d_in[7];
    const float* bih1 = (const float*)d_in[8];
    const float* bhh1 = (const float*)d_in[9];
    const float* Wout = (const float*)d_in[10];
    const float* bout = (const float*)d_in[11];
    float* out = (float*)d_out;

    const int n = in_sizes[0];
    const int chunks = (n + CHUNK - 1) / CHUNK;   // 2048 for n=524288 -> 2 waves/SIMD

    lstm_opt_kernel<<<chunks, 64, 0, stream>>>(grad, par, Wih0, Whh0, bih0, bhh0,
                                               Wih1, Whh1, bih1, bhh1, Wout, bout,
                                               out, n);
}